// Round 4
// baseline (428.083 us; speedup 1.0000x reference)
//
#include <hip/hip_runtime.h>
#include <hip/hip_bf16.h>

// WindowAttention3D MFMA round 3.
// k0 : qkv_w/proj_w -> bf16 pre-swizzled into MFMA B-fragment order
//      (GEMMs read B-frags straight from global; no weight LDS staging).
// k0b: bm = (bias+mask)*log2e, bf16, in C/D fragment order; pads -1e30.
//      Lives in d_out (scratch until k3 overwrites it; stream-ordered).
// k1 : qkv GEMM, 128 rows/block -> q*(scale*log2e), k, v bf16 [b][h][98][32]
// k2 : per (b,h): S=QK^T + bm, softmax via exp2 (no max pass; bounded scores),
//      PV -> o bf16 [b][n][128]
// k3 : proj GEMM, 128 rows/block -> fp32 out
// ws: q,k,v,o (4 x 25,690,112 bf16) + wqbf(49152) + wpbf(16384) bf16

#define NTOK 98
#define NN (NTOK * NTOK)
#define LOG2E 1.4426950408889634f
#define QSCALE (0.17677669529663687f * LOG2E)

typedef short bf16x8 __attribute__((ext_vector_type(8)));
typedef float f32x4 __attribute__((ext_vector_type(4)));
#define MFMA(a, b, c) __builtin_amdgcn_mfma_f32_16x16x32_bf16(a, b, c, 0, 0, 0)

static __device__ __forceinline__ unsigned short f2bf(float f) {
  union { float f; unsigned int i; } x; x.f = f;
  unsigned int u = x.i;
  unsigned int rnd = ((u >> 16) & 1u) + 0x7fffu;  // RNE
  return (unsigned short)((u + rnd) >> 16);
}
static __device__ __forceinline__ float bf2f(short s) {
  union { unsigned int i; float f; } x;
  x.i = ((unsigned int)(unsigned short)s) << 16;
  return x.f;
}

// ---------------- k0: weights -> bf16, B-fragment order ----------------------
// frag idx = ((tile)*64 + lane)*8 + j ; element = W[n=tile_n*16+(lane&15)]
//                                               [k=tile_k*32+(lane>>4)*8+j]
__global__ void k0_w(const float* __restrict__ qkv_w, const float* __restrict__ proj_w,
                     unsigned short* __restrict__ wqbf, unsigned short* __restrict__ wpbf) {
  int idx = blockIdx.x * 256 + threadIdx.x;  // 65536 total
  if (idx < 49152) {
    int j = idx & 7, lane = (idx >> 3) & 63, kt = (idx >> 9) & 3;
    int nt = (idx >> 11) & 7, g = idx >> 14;
    int n = nt * 16 + (lane & 15), k = kt * 32 + (lane >> 4) * 8 + j;
    wqbf[idx] = f2bf(qkv_w[(size_t)(g * 128 + n) * 128 + k]);
  } else {
    int i2 = idx - 49152;
    int j = i2 & 7, lane = (i2 >> 3) & 63, kt = (i2 >> 9) & 3, nt = i2 >> 11;
    int n = nt * 16 + (lane & 15), k = kt * 32 + (lane >> 4) * 8 + j;
    wpbf[i2] = f2bf(proj_w[(size_t)n * 128 + k]);
  }
}

// ---------------- k0b: fused (bias+mask)*log2e in C/D fragment order ---------
__global__ void k0b_bm(const float* __restrict__ table, const int* __restrict__ rel,
                       const float* __restrict__ mask, unsigned short* __restrict__ bm) {
  const int wmodh = blockIdx.x, mt = blockIdx.y;
  const int wmod = wmodh >> 2, h = wmodh & 3;
  const int t = threadIdx.x;
  const int lane = t >> 2, reg = t & 3;
  const int quad = lane >> 4, L15 = lane & 15;
  const int row = mt * 16 + quad * 4 + reg;
  bf16x8 v8;
#pragma unroll
  for (int nt = 0; nt < 8; ++nt) {
    float v = -1.0e30f;
    int col = nt * 16 + L15;
    if (nt < 7 && row < NTOK && col < NTOK) {
      int nm = row * NTOK + col;
      v = (table[rel[nm] * 4 + h] + mask[(size_t)wmod * NN + nm]) * LOG2E;
    }
    v8[nt] = (short)f2bf(v);
  }
  *(bf16x8*)&bm[(((size_t)wmodh * 7 + mt) << 11) + (lane << 5) + (reg << 3)] = v8;
}

// ---------------- k1: QKV GEMM, 128 rows x 384 cols per block ----------------
__global__ __launch_bounds__(256) void k1_qkv(const float* __restrict__ x,
                                              const unsigned short* __restrict__ wqbf,
                                              const float* __restrict__ qkv_b,
                                              unsigned short* __restrict__ q,
                                              unsigned short* __restrict__ k,
                                              unsigned short* __restrict__ v) {
  __shared__ unsigned short xt[128 * 136];
  const int t = threadIdx.x;
  const int r0 = blockIdx.x * 128;
  const int wv = t >> 6, lane = t & 63, L15 = lane & 15, quad = lane >> 4;

#pragma unroll
  for (int i = 0; i < 16; ++i) {  // 128x128 fp32 -> bf16 LDS
    int idx = t + (i << 8);
    int row = idx >> 5, c4 = idx & 31;
    float4 xv = *(const float4*)&x[(size_t)(r0 + row) * 128 + c4 * 4];
    ushort4 pk; pk.x = f2bf(xv.x); pk.y = f2bf(xv.y); pk.z = f2bf(xv.z); pk.w = f2bf(xv.w);
    *(ushort4*)&xt[row * 136 + c4 * 4] = pk;
  }
  __syncthreads();

  bf16x8 af[2][4];  // two 16-row strips per wave, shared across all col-tiles
#pragma unroll
  for (int p = 0; p < 2; ++p)
#pragma unroll
    for (int kt = 0; kt < 4; ++kt)
      af[p][kt] = *(const bf16x8*)&xt[(wv * 32 + p * 16 + L15) * 136 + kt * 32 + quad * 8];

  for (int g = 0; g < 3; ++g) {
    unsigned short* dst = (g == 0) ? q : ((g == 1) ? k : v);
    const float sc = (g == 0) ? QSCALE : 1.0f;
#pragma unroll
    for (int nt = 0; nt < 8; ++nt) {
      f32x4 a0 = {0.f, 0.f, 0.f, 0.f}, a1 = {0.f, 0.f, 0.f, 0.f};
#pragma unroll
      for (int kt = 0; kt < 4; ++kt) {
        bf16x8 b = *(const bf16x8*)&wqbf[((((g * 8 + nt) * 4 + kt)) << 9) + lane * 8];
        a0 = MFMA(af[0][kt], b, a0);
        a1 = MFMA(af[1][kt], b, a1);
      }
      float bias = qkv_b[g * 128 + nt * 16 + L15];
      int h = nt >> 1, dd = ((nt & 1) << 4) + L15;
#pragma unroll
      for (int reg = 0; reg < 4; ++reg) {
        int R0 = r0 + wv * 32 + quad * 4 + reg;
        int b0 = R0 / NTOK, n0 = R0 - b0 * NTOK;
        dst[((size_t)(b0 * 4 + h) * NTOK + n0) * 32 + dd] = f2bf((a0[reg] + bias) * sc);
        int R1 = R0 + 16;
        int b1 = R1 / NTOK, n1 = R1 - b1 * NTOK;
        dst[((size_t)(b1 * 4 + h) * NTOK + n1) * 32 + dd] = f2bf((a1[reg] + bias) * sc);
      }
    }
  }
}

// ---------------- k2: MFMA attention, one block per (window, head) -----------
__global__ __launch_bounds__(256) void k2_attn(const unsigned short* __restrict__ qg,
                                               const unsigned short* __restrict__ kg,
                                               const unsigned short* __restrict__ vg,
                                               const unsigned short* __restrict__ bm,
                                               unsigned short* __restrict__ og) {
  __shared__ unsigned short sK[112 * 40];      // [n][k], rows 98..111 zeroed
  __shared__ unsigned short sVt[32 * 136];     // [d][m], cols 98..127 zeroed
  __shared__ unsigned short sP[4 * 16 * 136];  // per-wave P strip [m][n]
  const int t = threadIdx.x;
  const int bh = blockIdx.x, bw = bh >> 2, h = bh & 3;
  const int wmodh = ((bw & 255) << 2) + h;
  const size_t base = (size_t)bh * 3136;
  const int wv = t >> 6, lane = t & 63, L15 = lane & 15, quad = lane >> 4;
  unsigned short* myP = sP + wv * (16 * 136);

  // pads (all disjoint from staging writes -> single barrier)
  for (int i = t; i < 280; i += 256) *(unsigned int*)&sK[3920 + i * 2] = 0;
  for (int j = lane; j < 128; j += 64) {  // myP cols 112..127
    int r = j >> 3, cp = j & 7;
    *(unsigned int*)&myP[r * 136 + 112 + cp * 2] = 0;
  }
  for (int i = t; i < 392; i += 256) {  // K rows via uint4
    int row = i >> 2, kq = i & 3;
    *(uint4*)&sK[row * 40 + kq * 8] = ((const uint4*)kg)[(size_t)bh * 392 + i];
  }
  for (int i = t; i < 1024; i += 256) {  // V^T, cols >=98 zeroed
    int n = i >> 3, d4 = i & 7;
    unsigned int ux = 0, uy = 0;
    if (n < NTOK) {
      uint2 u = *(const uint2*)&vg[base + n * 32 + d4 * 4];
      ux = u.x; uy = u.y;
    }
    sVt[(d4 * 4 + 0) * 136 + n] = (unsigned short)(ux & 0xffffu);
    sVt[(d4 * 4 + 1) * 136 + n] = (unsigned short)(ux >> 16);
    sVt[(d4 * 4 + 2) * 136 + n] = (unsigned short)(uy & 0xffffu);
    sVt[(d4 * 4 + 3) * 136 + n] = (unsigned short)(uy >> 16);
  }
  __syncthreads();

  auto do_strip = [&](int mt) {
    const unsigned short* bmp = bm + (((size_t)wmodh * 7 + mt) << 11) + (lane << 5);
    bf16x8 bmv[4];
#pragma unroll
    for (int reg = 0; reg < 4; ++reg) bmv[reg] = *(const bf16x8*)&bmp[reg << 3];
    bf16x8 aq = *(const bf16x8*)&qg[base + (size_t)(mt * 16 + L15) * 32 + quad * 8];
    f32x4 s[7];
#pragma unroll
    for (int nt = 0; nt < 7; ++nt) {
      bf16x8 bk = *(const bf16x8*)&sK[(nt * 16 + L15) * 40 + quad * 8];
      f32x4 z = {0.f, 0.f, 0.f, 0.f};
      s[nt] = MFMA(aq, bk, z);
    }
#pragma unroll
    for (int reg = 0; reg < 4; ++reg) {
      float sum = 0.f;
#pragma unroll
      for (int nt = 0; nt < 7; ++nt) {  // no max pass: scores bounded, pads underflow to 0
        float e = exp2f(fminf(s[nt][reg] + bf2f(bmv[reg][nt]), 80.f));
        s[nt][reg] = e; sum += e;
      }
#pragma unroll
      for (int d = 1; d < 16; d <<= 1) sum += __shfl_xor(sum, d, 64);
      float rs = __builtin_amdgcn_rcpf(sum);
#pragma unroll
      for (int nt = 0; nt < 7; ++nt)
        myP[(quad * 4 + reg) * 136 + nt * 16 + L15] = f2bf(s[nt][reg] * rs);
    }
    f32x4 o0 = {0.f, 0.f, 0.f, 0.f}, o1 = {0.f, 0.f, 0.f, 0.f};
#pragma unroll
    for (int kt = 0; kt < 4; ++kt) {
      bf16x8 ap  = *(const bf16x8*)&myP[L15 * 136 + kt * 32 + quad * 8];
      bf16x8 bv0 = *(const bf16x8*)&sVt[L15 * 136 + kt * 32 + quad * 8];
      bf16x8 bv1 = *(const bf16x8*)&sVt[(16 + L15) * 136 + kt * 32 + quad * 8];
      o0 = MFMA(ap, bv0, o0);
      o1 = MFMA(ap, bv1, o1);
    }
#pragma unroll
    for (int reg = 0; reg < 4; ++reg) {
      int n = mt * 16 + quad * 4 + reg;
      if (n < NTOK) {
        size_t ob = ((size_t)bw * NTOK + n) * 128 + h * 32;
        og[ob + L15]      = f2bf(o0[reg]);
        og[ob + 16 + L15] = f2bf(o1[reg]);
      }
    }
  };
  do_strip(wv * 2);
  if (wv < 3) do_strip(wv * 2 + 1);
}

// ---------------- k3: proj GEMM, 128 rows x 128 cols per block ---------------
__global__ __launch_bounds__(256) void k3_proj(const unsigned short* __restrict__ og,
                                               const unsigned short* __restrict__ wpbf,
                                               const float* __restrict__ pb,
                                               float* __restrict__ out) {
  __shared__ unsigned short ot[128 * 136];
  const int t = threadIdx.x;
  const int r0 = blockIdx.x * 128;
  const int wv = t >> 6, lane = t & 63, L15 = lane & 15, quad = lane >> 4;

#pragma unroll
  for (int i = 0; i < 8; ++i) {  // 128x128 bf16 via uint4
    int idx = t + (i << 8);
    int row = idx >> 4, kq = idx & 15;
    *(uint4*)&ot[row * 136 + kq * 8] = ((const uint4*)og)[(size_t)(r0 + row) * 16 + kq];
  }
  __syncthreads();

  bf16x8 af[2][4];
#pragma unroll
  for (int p = 0; p < 2; ++p)
#pragma unroll
    for (int kt = 0; kt < 4; ++kt)
      af[p][kt] = *(const bf16x8*)&ot[(wv * 32 + p * 16 + L15) * 136 + kt * 32 + quad * 8];

#pragma unroll
  for (int nt = 0; nt < 8; ++nt) {
    f32x4 a0 = {0.f, 0.f, 0.f, 0.f}, a1 = {0.f, 0.f, 0.f, 0.f};
#pragma unroll
    for (int kt = 0; kt < 4; ++kt) {
      bf16x8 b = *(const bf16x8*)&wpbf[((nt * 4 + kt) << 9) + lane * 8];
      a0 = MFMA(af[0][kt], b, a0);
      a1 = MFMA(af[1][kt], b, a1);
    }
    float bias = pb[nt * 16 + L15];
#pragma unroll
    for (int reg = 0; reg < 4; ++reg) {
      size_t R0 = (size_t)r0 + wv * 32 + quad * 4 + reg;
      out[R0 * 128 + nt * 16 + L15] = a0[reg] + bias;
      out[(R0 + 16) * 128 + nt * 16 + L15] = a1[reg] + bias;
    }
  }
}

extern "C" void kernel_launch(void* const* d_in, const int* in_sizes, int n_in,
                              void* d_out, int out_size, void* d_ws, size_t ws_size,
                              hipStream_t stream) {
  (void)in_sizes; (void)n_in; (void)out_size; (void)ws_size;
  const float* x      = (const float*)d_in[0];
  const float* mask   = (const float*)d_in[1];
  const float* qkv_w  = (const float*)d_in[2];
  const float* qkv_b  = (const float*)d_in[3];
  const float* proj_w = (const float*)d_in[4];
  const float* proj_b = (const float*)d_in[5];
  const float* table  = (const float*)d_in[6];
  const int*   rel    = (const int*)d_in[7];
  float* out = (float*)d_out;

  const size_t QS = (size_t)2048 * 4 * NTOK * 32;  // 25,690,112
  unsigned short* q    = (unsigned short*)d_ws;
  unsigned short* k    = q + QS;
  unsigned short* v    = k + QS;
  unsigned short* o    = v + QS;  // [b][n][128] bf16
  unsigned short* wqbf = o + QS;
  unsigned short* wpbf = wqbf + 49152;
  unsigned short* bm   = (unsigned short*)d_out;  // scratch until k3 overwrites

  k0_w<<<256, 256, 0, stream>>>(qkv_w, proj_w, wqbf, wpbf);
  k0b_bm<<<dim3(1024, 7), 256, 0, stream>>>(table, rel, mask, bm);
  k1_qkv<<<200704 / 128, 256, 0, stream>>>(x, wqbf, qkv_b, q, k, v);
  k2_attn<<<2048 * 4, 256, 0, stream>>>(q, k, v, bm, o);
  k3_proj<<<200704 / 128, 256, 0, stream>>>(o, wpbf, proj_b, out);
}